// Round 7
// baseline (220.652 us; speedup 1.0000x reference)
//
#include <hip/hip_runtime.h>

typedef unsigned short u16;
typedef unsigned int u32;

typedef __attribute__((ext_vector_type(8))) short bf16x8;
typedef __attribute__((ext_vector_type(4))) float f32x4;

__device__ __forceinline__ float bf2f(u16 u) {
    return __uint_as_float(((u32)u) << 16);
}
__device__ __forceinline__ u16 f2bf(float f) {
    u32 x = __float_as_uint(f);
    return (u16)((x + 0x7fffu + ((x >> 16) & 1u)) >> 16);
}

// block-uniform dtype flag: true if x is bf16, false if fp32.
__device__ __forceinline__ bool block_isbf(const u16* __restrict__ x, float* sflag) {
    int tid = threadIdx.x;
    if (tid < 64) {
        u16 v = x[tid * 2];
        u32 ex = (v >> 7) & 0xFFu;
        unsigned long long m = __ballot(ex >= 90u && ex <= 140u);
        if (tid == 0) *sflag = (m == ~0ull) ? 1.0f : 0.0f;
    }
    __syncthreads();
    return *sflag != 0.0f;
}

// 32-lane-group gather accumulate: ax,ay += feats of rows csr[s0..s1) at u32-col `lane`.
__device__ __forceinline__ void gather_accum(
    const u32* __restrict__ fl, const u16* __restrict__ csr,
    int s0, int s1, int lane, float& ax, float& ay) {
    int deg = s1 - s0;
    for (int base = 0; base < deg; base += 32) {
        int m = min(deg - base, 32);
        int idx = 0;
        if (lane < m) idx = (int)csr[s0 + base + lane];
        int j = 0;
        for (; j + 8 <= m; j += 8) {
            u32 wv[8];
#pragma unroll
            for (int u = 0; u < 8; u++) {
                int sv = __shfl(idx, j + u, 32);
                wv[u] = fl[(size_t)sv * 32];
            }
#pragma unroll
            for (int u = 0; u < 8; u++) {
                ax += bf2f((u16)(wv[u] & 0xFFFFu));
                ay += bf2f((u16)(wv[u] >> 16));
            }
        }
        for (; j + 4 <= m; j += 4) {
            u32 wv[4];
#pragma unroll
            for (int u = 0; u < 4; u++) {
                int sv = __shfl(idx, j + u, 32);
                wv[u] = fl[(size_t)sv * 32];
            }
#pragma unroll
            for (int u = 0; u < 4; u++) {
                ax += bf2f((u16)(wv[u] & 0xFFFFu));
                ay += bf2f((u16)(wv[u] >> 16));
            }
        }
        for (; j < m; j++) {
            int sv = __shfl(idx, j, 32);
            u32 wa = fl[(size_t)sv * 32];
            ax += bf2f((u16)(wa & 0xFFFFu));
            ay += bf2f((u16)(wa >> 16));
        }
    }
}

__global__ void k_zero(int* __restrict__ p, int n) {
    int i = blockIdx.x * 256 + threadIdx.x;
    if (i < n) p[i] = 0;
}
__global__ void k_cnt(const int* __restrict__ dst, int* __restrict__ cnt, int E) {
    int e = blockIdx.x * 256 + threadIdx.x;
    if (e < E) atomicAdd(&cnt[dst[e]], 1);
}

// per-block exclusive scan -> row_start (local), block sums -> bsum
__global__ void k_partial(const int* __restrict__ cnt, int* __restrict__ row_start,
                          int* __restrict__ bsum, int n) {
    __shared__ int sd[256];
    int tid = threadIdx.x;
    int i = blockIdx.x * 256 + tid;
    int v = (i < n) ? cnt[i] : 0;
    sd[tid] = v;
    __syncthreads();
    for (int s = 1; s < 256; s <<= 1) {
        int t = (tid >= s) ? sd[tid - s] : 0;
        __syncthreads();
        sd[tid] += t;
        __syncthreads();
    }
    if (i < n) row_start[i] = sd[tid] - v;   // local exclusive
    if (tid == 255) bsum[blockIdx.x] = sd[255];
}
// merged: add block-prefix (computed per-block by 256-wide reduce), init cursor/dinv
__global__ void k_scanadd(const int* __restrict__ cnt, int* __restrict__ row_start,
                          int* __restrict__ cursor, const int* __restrict__ bsum,
                          float* __restrict__ dinv, int n, int nb, int E) {
    __shared__ int sd[256];
    int tid = threadIdx.x;
    int bid = blockIdx.x;
    sd[tid] = (tid < nb && tid < bid) ? bsum[tid] : 0;
    __syncthreads();
    for (int s = 128; s > 0; s >>= 1) {
        if (tid < s) sd[tid] += sd[tid + s];
        __syncthreads();
    }
    int off = sd[0];
    int i = bid * 256 + tid;
    if (i < n) {
        int rs = row_start[i] + off;
        row_start[i] = rs;
        cursor[i] = rs;
        dinv[i] = rsqrtf((float)(cnt[i] + 1));   // +1 self-loop
    }
    if (bid == 0 && tid == 0) row_start[n] = E;
}

// Fused: [0,fillB) CSR-fill | [fillB,fillB+17) weight-canonicalize | rest scale-x -> gxt.
// wc layout (u16): [0,8192) W1t[n*64+k] | [8192,16384) W2t[n*128+k]
//                  [16384,16512) b1 | [16512,16576) b2
__global__ __launch_bounds__(256) void k_fillprep(
    const int* __restrict__ src, const int* __restrict__ dst,
    int* __restrict__ cursor, u16* __restrict__ csr, int E, int fillB,
    const void* __restrict__ W1, const void* __restrict__ b1,
    const void* __restrict__ W2, const void* __restrict__ b2,
    u16* __restrict__ wc,
    const void* __restrict__ x, const float* __restrict__ dinv,
    u16* __restrict__ gxt, int n16) {
    __shared__ float sflag;
    const int bid = blockIdx.x;
    const int tid = threadIdx.x;
    if (bid < fillB) {
        int e = bid * 256 + tid;
        if (e < E) {
            int p = atomicAdd(&cursor[dst[e]], 1);
            csr[p] = (u16)src[e];
        }
    } else if (bid < fillB + 17) {
        bool isbf = block_isbf((const u16*)x, &sflag);
        int cb = bid - fillB;
        for (int i = cb * 256 + tid; i < 16576; i += 17 * 256) {
            const void* s; int off;
            if (i < 8192)       { int nn = i >> 6, k = i & 63;  s = W1; off = k * 128 + nn; }
            else if (i < 16384) { int j = i - 8192; int nn = j >> 7, k = j & 127; s = W2; off = k * 64 + nn; }
            else if (i < 16512) { s = b1; off = i - 16384; }
            else                { s = b2; off = i - 16512; }
            wc[i] = isbf ? ((const u16*)s)[off] : f2bf(((const float*)s)[off]);
        }
    } else {
        // xt = bf16(x * dinv[row]) -> gxt (lives in d_out scratch)
        bool isbf = block_isbf((const u16*)x, &sflag);
        int idx = (bid - fillB - 17) * 256 + tid;
        if (idx >= n16) return;
        int r = idx >> 4;
        float di = dinv[r];
        float4 v;
        if (isbf) {
            ushort4 u = ((const ushort4*)x)[idx];
            v.x = bf2f(u.x); v.y = bf2f(u.y); v.z = bf2f(u.z); v.w = bf2f(u.w);
        } else {
            v = ((const float4*)x)[idx];
        }
        ushort4 o;
        o.x = f2bf(v.x * di); o.y = f2bf(v.y * di);
        o.z = f2bf(v.z * di); o.w = f2bf(v.w * di);
        ((ushort4*)gxt)[idx] = o;
    }
}

// FUSED gather1 + MFMA 2-layer MLP on a 32-row tile (53 KB LDS):
//   acc1 = self + gather(xt)            (fp32 regs, x dinv, round once)
//   h    = relu( acc1b @ W1 + b1 )      [32 x 128]
//   ht2  = ( h @ W2 ) * dinv[r]         [32 x 64] -> bf16 outb
// mfma_f32_16x16x32_bf16; A/B frag: [idx=lane&15][k=quad*8+j]; C/D: row=quad*4+reg, col=lane&15.
__global__ __launch_bounds__(256) void k_gmlp(
    const u32* __restrict__ feat, const int* __restrict__ row_start,
    const u16* __restrict__ csr, const u16* __restrict__ wc,
    const float* __restrict__ dinv, u16* __restrict__ outb, int n) {
    __shared__ __align__(16) u16 As[32 * 72];      //  4.5 KB
    __shared__ __align__(16) u16 W1t[128 * 72];    // 18.0 KB
    __shared__ __align__(16) u16 W2t[64 * 136];    // 17.0 KB
    __shared__ __align__(16) u16 Hs[32 * 136];     //  8.5 KB
    __shared__ float b1s[128];
    __shared__ float dvs[32];
    const int tid = threadIdx.x;
    const int row0 = blockIdx.x * 32;

    if (tid < 32) {
        int r = row0 + tid;
        dvs[tid] = (r < n) ? dinv[r] : 0.f;
    } else if (tid < 160) {
        b1s[tid - 32] = bf2f(wc[16384 + tid - 32]);
    }
    // stage weights
    for (int i = tid; i < 4096; i += 256) {
        int nn = i >> 5, kk = i & 31;
        *(u32*)&W1t[nn * 72 + kk * 2] = ((const u32*)wc)[i];
    }
    for (int i = tid; i < 4096; i += 256) {
        int nn = i >> 6, kk = i & 63;
        *(u32*)&W2t[nn * 136 + kk * 2] = ((const u32*)wc)[4096 + i];
    }
    // gather acc1 for our 32 rows: 8 groups x 32 lanes, 4 rows/group
    {
        const int grp = tid >> 5;
        const int lane = tid & 31;
        const u32* fl = feat + lane;
        for (int rr = grp; rr < 32; rr += 8) {
            int row = row0 + rr;
            float ax = 0.f, ay = 0.f;
            if (row < n) {
                u32 w = fl[(size_t)row * 32];            // self-loop
                ax = bf2f((u16)(w & 0xFFFFu));
                ay = bf2f((u16)(w >> 16));
                gather_accum(fl, csr, row_start[row], row_start[row + 1], lane, ax, ay);
                float di = dinv[row];
                ax *= di; ay *= di;
            }
            u32 v = (u32)f2bf(ax) | ((u32)f2bf(ay) << 16);
            *(u32*)&As[rr * 72 + lane * 2] = v;
        }
    }
    __syncthreads();

    const int wave = tid >> 6;     // 0..3
    const int lane = tid & 63;
    const int q = lane >> 4;       // quad
    const int ln = lane & 15;

    // ---- GEMM1: [32x64] @ [64x128] ----
    bf16x8 a[2][2];
#pragma unroll
    for (int mt = 0; mt < 2; mt++)
#pragma unroll
        for (int ks = 0; ks < 2; ks++)
            a[mt][ks] = *(const bf16x8*)&As[(mt * 16 + ln) * 72 + ks * 32 + q * 8];

    f32x4 c1[2][2];   // [ntl][mt]
#pragma unroll
    for (int ntl = 0; ntl < 2; ntl++)
#pragma unroll
        for (int mt = 0; mt < 2; mt++) c1[ntl][mt] = (f32x4){0.f, 0.f, 0.f, 0.f};

#pragma unroll
    for (int ntl = 0; ntl < 2; ntl++) {
        int nt = wave * 2 + ntl;
        bf16x8 b0 = *(const bf16x8*)&W1t[(nt * 16 + ln) * 72 + 0 + q * 8];
        bf16x8 b1f = *(const bf16x8*)&W1t[(nt * 16 + ln) * 72 + 32 + q * 8];
#pragma unroll
        for (int mt = 0; mt < 2; mt++) {
            c1[ntl][mt] = __builtin_amdgcn_mfma_f32_16x16x32_bf16(a[mt][0], b0, c1[ntl][mt], 0, 0, 0);
            c1[ntl][mt] = __builtin_amdgcn_mfma_f32_16x16x32_bf16(a[mt][1], b1f, c1[ntl][mt], 0, 0, 0);
        }
    }
    // epilogue1: +b1, relu -> Hs (bf16)
#pragma unroll
    for (int ntl = 0; ntl < 2; ntl++) {
        int col = (wave * 2 + ntl) * 16 + ln;
        float bb = b1s[col];
#pragma unroll
        for (int mt = 0; mt < 2; mt++)
#pragma unroll
            for (int r = 0; r < 4; r++) {
                int hrow = mt * 16 + q * 4 + r;
                Hs[hrow * 136 + col] = f2bf(fmaxf(c1[ntl][mt][r] + bb, 0.f));
            }
    }
    __syncthreads();

    // ---- GEMM2: [32x128] @ [128x64] ----
    f32x4 c2[2];
    c2[0] = (f32x4){0.f, 0.f, 0.f, 0.f};
    c2[1] = (f32x4){0.f, 0.f, 0.f, 0.f};
#pragma unroll
    for (int ks = 0; ks < 4; ks++) {
        bf16x8 bb = *(const bf16x8*)&W2t[(wave * 16 + ln) * 136 + ks * 32 + q * 8];
#pragma unroll
        for (int mt = 0; mt < 2; mt++) {
            bf16x8 aa = *(const bf16x8*)&Hs[(mt * 16 + ln) * 136 + ks * 32 + q * 8];
            c2[mt] = __builtin_amdgcn_mfma_f32_16x16x32_bf16(aa, bb, c2[mt], 0, 0, 0);
        }
    }
    // epilogue2: *dinv -> bf16 outb
#pragma unroll
    for (int mt = 0; mt < 2; mt++)
#pragma unroll
        for (int r = 0; r < 4; r++) {
            int rloc = mt * 16 + q * 4 + r;
            int row = row0 + rloc;
            if (row < n) {
                int col = wave * 16 + ln;
                outb[(size_t)row * 64 + col] = f2bf(c2[mt][r] * dvs[rloc]);
            }
        }
}

// final gather: out[d] = bf16/f32( (ht2[d] + sum ht2[csr]) * dinv[d] + b2 )
__global__ __launch_bounds__(256) void k_gfinal(
    const u32* __restrict__ feat, const int* __restrict__ row_start,
    const u16* __restrict__ csr, const float* __restrict__ dinv,
    const u16* __restrict__ b2c, const void* __restrict__ xdet,
    void* __restrict__ outp, int n) {
    __shared__ float sflag;
    bool isbf = block_isbf((const u16*)xdet, &sflag);
    int t = blockIdx.x * 256 + threadIdx.x;
    int d = t >> 5;
    int lane = t & 31;
    if (d >= n) return;
    const u32* fl = feat + lane;
    u32 w = fl[(size_t)d * 32];                 // self-loop
    float ax = bf2f((u16)(w & 0xFFFFu));
    float ay = bf2f((u16)(w >> 16));
    gather_accum(fl, csr, row_start[d], row_start[d + 1], lane, ax, ay);
    float di = dinv[d];
    ax = ax * di + bf2f(b2c[2 * lane + 0]);
    ay = ay * di + bf2f(b2c[2 * lane + 1]);
    if (isbf) {
        u32 o = (u32)f2bf(ax) | ((u32)f2bf(ay) << 16);
        ((u32*)outp)[(size_t)d * 32 + lane] = o;
    } else {
        ((float2*)outp)[(size_t)d * 32 + lane] = make_float2(ax, ay);
    }
}

extern "C" void kernel_launch(void* const* d_in, const int* in_sizes, int n_in,
                              void* d_out, int out_size, void* d_ws, size_t ws_size,
                              hipStream_t stream) {
    const void* x  = d_in[0];
    const int* ei  = (const int*)d_in[1];
    const void* W1 = d_in[2];
    const void* b1 = d_in[3];
    const void* W2 = d_in[4];
    const void* b2 = d_in[5];

    const int N = in_sizes[0] / 64;   // 50000  (must be < 65536 for u16 csr)
    const int E = in_sizes[1] / 2;    // 800000
    const int* src = ei;
    const int* dst = ei + E;

    // workspace (~8.9 MB). xt lives in d_out (scratch until k_gfinal rewrites it).
    float* ws = (float*)d_ws;
    const int NP = ((N + 64) + 63) & ~63;
    float* dinv    = ws;
    int* cnt       = (int*)(ws + NP);
    int* row_start = cnt + N;
    int* cursor    = row_start + ((N + 64) & ~63);
    int* bsum      = cursor + N;
    u16* csr       = (u16*)(bsum + 256);
    u16* wc        = (u16*)(((size_t)(csr + E) + 255) & ~(size_t)255);
    u16* bufB      = (u16*)(((size_t)(wc + 16576) + 255) & ~(size_t)255);
    u16* gxt       = (u16*)d_out;     // xt scratch in d_out

    const int n16 = N * 16;
    const int nb = (N + 255) / 256;          // 196 (<=256 required)
    const int gth = (N * 32 + 255) / 256;    // gather grid
    const int fillB = (E + 255) / 256;
    const int prepB = fillB + 17 + (n16 + 255) / 256;
    dim3 blk(256);

    k_zero<<<dim3(nb), blk, 0, stream>>>(cnt, N);
    k_cnt<<<dim3(fillB), blk, 0, stream>>>(dst, cnt, E);
    k_partial<<<dim3(nb), blk, 0, stream>>>(cnt, row_start, bsum, N);
    k_scanadd<<<dim3(nb), blk, 0, stream>>>(cnt, row_start, cursor, bsum, dinv, N, nb, E);
    // csr fill + weight canonicalize + xt = bf16(x*dinv) -> d_out
    k_fillprep<<<dim3(prepB), blk, 0, stream>>>(src, dst, cursor, csr, E, fillB,
                                                W1, b1, W2, b2, wc, x, dinv, gxt, n16);
    // fused: acc1 = gather(xt); ht2 = (relu(dinv*acc1 @ W1 + b1) @ W2)*dinv -> bufB
    k_gmlp<<<dim3((N + 31) / 32), blk, 0, stream>>>((const u32*)gxt, row_start, csr,
                                                    wc, dinv, bufB, N);
    // out = bf16( (ht2[d]+gather(ht2))*dinv + b2 ) -> d_out
    k_gfinal<<<dim3(gth), blk, 0, stream>>>((const u32*)bufB, row_start, csr,
                                            dinv, wc + 16512, x, d_out, N);
}